// Round 2
// baseline (882.259 us; speedup 1.0000x reference)
//
#include <hip/hip_runtime.h>

#define NFEAT 128
#define NXCD 8

static inline size_t align_up(size_t x, size_t a) { return (x + a - 1) & ~(a - 1); }

__device__ inline unsigned xcc_id() {
  unsigned x;
  asm volatile("s_getreg_b32 %0, hwreg(HW_REG_XCC_ID)" : "=s"(x));
  return x & (NXCD - 1);
}

// ---------------- degree histogram: per-physical-XCD slices, L2-local atomics ----------------
__global__ __launch_bounds__(256) void k_hist8(const int* __restrict__ src,
                                               const int* __restrict__ dst,
                                               unsigned* __restrict__ slice_out,
                                               unsigned* __restrict__ slice_in,
                                               int E, int N) {
  const unsigned x = xcc_id();
  unsigned* mo = slice_out + (size_t)x * N;
  unsigned* mi = slice_in + (size_t)x * N;
  for (int i = blockIdx.x * 256 + threadIdx.x; i < E; i += gridDim.x * 256) {
    int s = src[i];
    int d = dst[i];
    __hip_atomic_fetch_add(&mo[s], 1u, __ATOMIC_RELAXED, __HIP_MEMORY_SCOPE_WORKGROUP);
    __hip_atomic_fetch_add(&mi[d], 1u, __ATOMIC_RELAXED, __HIP_MEMORY_SCOPE_WORKGROUP);
  }
}

// reduce 8 slices -> counts, rsqrt factors
__global__ __launch_bounds__(256) void k_rsq8(const unsigned* __restrict__ slice_out,
                                              const unsigned* __restrict__ slice_in,
                                              float* __restrict__ rsq_out,
                                              float* __restrict__ rsq_in,
                                              int* __restrict__ cnt_in, int N) {
  int i = blockIdx.x * 256 + threadIdx.x;
  if (i >= N) return;
  unsigned co = 0, ci = 0;
#pragma unroll
  for (int x = 0; x < NXCD; ++x) {
    co += slice_out[(size_t)x * N + i];
    ci += slice_in[(size_t)x * N + i];
  }
  cnt_in[i] = (int)ci;
  if (co < 1) co = 1;
  if (ci < 1) ci = 1;
  rsq_out[i] = 1.0f / sqrtf((float)co);
  rsq_in[i] = 1.0f / sqrtf((float)ci);
}

// ---------------- exclusive scan (3 phases) ----------------
__global__ __launch_bounds__(256) void k_scan1(const int* __restrict__ in,
                                               int* __restrict__ out,
                                               int* __restrict__ bsum, int n) {
  __shared__ int tmp[256];
  int t = threadIdx.x;
  int i = blockIdx.x * 256 + t;
  int v = (i < n) ? in[i] : 0;
  tmp[t] = v;
  __syncthreads();
  for (int off = 1; off < 256; off <<= 1) {
    int y = (t >= off) ? tmp[t - off] : 0;
    __syncthreads();
    tmp[t] += y;
    __syncthreads();
  }
  int incl = tmp[t];
  if (i < n) out[i] = incl - v;   // exclusive
  if (t == 255) bsum[blockIdx.x] = incl;
}

__global__ __launch_bounds__(512) void k_scan2(int* __restrict__ bsum,
                                               int* __restrict__ bscan, int nb) {
  __shared__ int tmp[512];
  int t = threadIdx.x;
  int v = (t < nb) ? bsum[t] : 0;
  tmp[t] = v;
  __syncthreads();
  for (int off = 1; off < 512; off <<= 1) {
    int y = (t >= off) ? tmp[t - off] : 0;
    __syncthreads();
    tmp[t] += y;
    __syncthreads();
  }
  bscan[t] = tmp[t] - v;          // exclusive
}

__global__ __launch_bounds__(256) void k_scan3(int* __restrict__ out,
                                               const int* __restrict__ bscan,
                                               int* __restrict__ cursor, int n, int E) {
  int i = blockIdx.x * 256 + threadIdx.x;
  if (i < n) {
    int r = out[i] + bscan[blockIdx.x];
    out[i] = r;
    cursor[i] = r;
  }
  if (i == 0) out[n] = E;
}

// ---------------- scatter edges into dst-CSR (device-scope cursors; placement must be global) ----
__global__ __launch_bounds__(256) void k_scatter(const int* __restrict__ src,
                                                 const int* __restrict__ dst,
                                                 int* __restrict__ cursor,
                                                 int* __restrict__ col, int E) {
  for (int i = blockIdx.x * 256 + threadIdx.x; i < E; i += gridDim.x * 256) {
    int d = dst[i];
    int p = atomicAdd(&cursor[d], 1);
    col[p] = src[i];
  }
}

// ---------------- fused pre-transform + SGEMM ----------------
// Y[r][c] = rsq_out[r] * sum_k f(X[r][k]) * W[k][c]
// mode 0: f = identity   mode 1: f = relu(x*bnscale[k]+bnshift[k])
#define GB_ROWS 64
#define GB_COLS 64
#define GK 16
#define XLD 68

__global__ __launch_bounds__(256) void k_gemm(
    const float* __restrict__ X, const float* __restrict__ W,
    float* __restrict__ Y, const float* __restrict__ rsq_out,
    const float* __restrict__ bnscale, const float* __restrict__ bnshift,
    int Nrows, int Ccols, int mode) {
  __shared__ __align__(16) float Xs[GK][XLD];  // transposed: Xs[k][r]
  __shared__ __align__(16) float Ws[GK][XLD];  // Ws[k][c]
  const int tid = threadIdx.x;
  const int tx = tid & 15;   // col group
  const int ty = tid >> 4;   // row group
  const int rowBase = blockIdx.x * GB_ROWS;
  const int colBase = blockIdx.y * GB_COLS;
  float acc[4][4] = {};

  for (int k0 = 0; k0 < NFEAT; k0 += GK) {
#pragma unroll
    for (int i = 0; i < 4; ++i) {
      int e = tid + i * 256;
      int r = e >> 4, k = e & 15;
      int gr = rowBase + r;
      float v = 0.0f;
      if (gr < Nrows) v = X[(size_t)gr * NFEAT + k0 + k];
      if (mode) {
        v = v * bnscale[k0 + k] + bnshift[k0 + k];
        v = v > 0.0f ? v : 0.0f;
      }
      Xs[k][r] = v;
    }
#pragma unroll
    for (int i = 0; i < 4; ++i) {
      int e = tid + i * 256;
      int k = e >> 6, c = e & 63;
      Ws[k][c] = W[(size_t)(k0 + k) * Ccols + colBase + c];
    }
    __syncthreads();
#pragma unroll
    for (int k = 0; k < GK; ++k) {
      const float4 xv = *(const float4*)&Xs[k][ty * 4];
      const float4 wv = *(const float4*)&Ws[k][tx * 4];
      acc[0][0] += xv.x * wv.x; acc[0][1] += xv.x * wv.y; acc[0][2] += xv.x * wv.z; acc[0][3] += xv.x * wv.w;
      acc[1][0] += xv.y * wv.x; acc[1][1] += xv.y * wv.y; acc[1][2] += xv.y * wv.z; acc[1][3] += xv.y * wv.w;
      acc[2][0] += xv.z * wv.x; acc[2][1] += xv.z * wv.y; acc[2][2] += xv.z * wv.z; acc[2][3] += xv.z * wv.w;
      acc[3][0] += xv.w * wv.x; acc[3][1] += xv.w * wv.y; acc[3][2] += xv.w * wv.z; acc[3][3] += xv.w * wv.w;
    }
    __syncthreads();
  }
#pragma unroll
  for (int i = 0; i < 4; ++i) {
    int gr = rowBase + ty * 4 + i;
    if (gr < Nrows) {
      float s = rsq_out[gr];
      float4 o = make_float4(acc[i][0] * s, acc[i][1] * s, acc[i][2] * s, acc[i][3] * s);
      *(float4*)&Y[(size_t)gr * Ccols + colBase + tx * 4] = o;
    }
  }
}

// ---------------- CSR SpMM: out[n] = rsq_in[n] * sum_{e in row n} xW[col[e]] + bias ----------------
template <int F>
__global__ __launch_bounds__(256) void k_spmm(const int* __restrict__ row_ptr,
                                              const int* __restrict__ colidx,
                                              const float* __restrict__ xW,
                                              float* __restrict__ out,
                                              const float* __restrict__ rsq_in,
                                              const float* __restrict__ bias, int Nrows) {
  constexpr int L = F / 4;                  // lanes per node
  const int node = blockIdx.x * (256 / L) + threadIdx.x / L;
  const int lane = threadIdx.x % L;
  if (node >= Nrows) return;
  const int e0 = row_ptr[node];
  const int e1 = row_ptr[node + 1];
  float4 acc = make_float4(0.f, 0.f, 0.f, 0.f);
  int e = e0;
  for (; e + 1 < e1; e += 2) {
    int s0 = colidx[e];
    int s1 = colidx[e + 1];
    float4 v0 = *(const float4*)&xW[(size_t)s0 * F + lane * 4];
    float4 v1 = *(const float4*)&xW[(size_t)s1 * F + lane * 4];
    acc.x += v0.x; acc.y += v0.y; acc.z += v0.z; acc.w += v0.w;
    acc.x += v1.x; acc.y += v1.y; acc.z += v1.z; acc.w += v1.w;
  }
  if (e < e1) {
    int s0 = colidx[e];
    float4 v0 = *(const float4*)&xW[(size_t)s0 * F + lane * 4];
    acc.x += v0.x; acc.y += v0.y; acc.z += v0.z; acc.w += v0.w;
  }
  const float sc = rsq_in[node];
  const float4 b = *(const float4*)&bias[lane * 4];
  float4 o = make_float4(acc.x * sc + b.x, acc.y * sc + b.y, acc.z * sc + b.z, acc.w * sc + b.w);
  *(float4*)&out[(size_t)node * F + lane * 4] = o;
}

// ---------------- BatchNorm stats + finalize ----------------
__global__ __launch_bounds__(256) void k_bn_stats(const float* __restrict__ h,
                                                  float* __restrict__ sum,
                                                  float* __restrict__ sumsq, int Nrows) {
  const int f = threadIdx.x & 127;
  const int half = threadIdx.x >> 7;
  float s = 0.f, ss = 0.f;
  for (int r = blockIdx.x * 2 + half; r < Nrows; r += gridDim.x * 2) {
    float v = h[(size_t)r * NFEAT + f];
    s += v;
    ss += v * v;
  }
  __shared__ float ls[256], lss[256];
  ls[threadIdx.x] = s;
  lss[threadIdx.x] = ss;
  __syncthreads();
  if (half == 0) {
    atomicAdd(&sum[f], ls[f] + ls[f + 128]);
    atomicAdd(&sumsq[f], lss[f] + lss[f + 128]);
  }
}

__global__ __launch_bounds__(128) void k_bn_final(const float* __restrict__ sum,
                                                  const float* __restrict__ sumsq,
                                                  const float* __restrict__ gamma,
                                                  const float* __restrict__ beta,
                                                  float* __restrict__ scale,
                                                  float* __restrict__ shift, int Nrows) {
  int f = threadIdx.x;
  float inv_n = 1.0f / (float)Nrows;
  float mean = sum[f] * inv_n;
  float var = sumsq[f] * inv_n - mean * mean;
  if (var < 0.f) var = 0.f;
  float sc = gamma[f] * (1.0f / sqrtf(var + 1e-5f));
  scale[f] = sc;
  shift[f] = beta[f] - mean * sc;
}

extern "C" void kernel_launch(void* const* d_in, const int* in_sizes, int n_in,
                              void* d_out, int out_size, void* d_ws, size_t ws_size,
                              hipStream_t stream) {
  const float* in_feat = (const float*)d_in[0];
  const int* src = (const int*)d_in[1];
  const int* dst = (const int*)d_in[2];
  const float* W0 = (const float*)d_in[3];
  const float* b0 = (const float*)d_in[4];
  const float* W1 = (const float*)d_in[5];
  const float* b1 = (const float*)d_in[6];
  const float* W2 = (const float*)d_in[7];
  const float* b2 = (const float*)d_in[8];
  const float* gamma0 = (const float*)d_in[9];
  const float* beta0 = (const float*)d_in[10];
  const float* gamma1 = (const float*)d_in[11];
  const float* beta1 = (const float*)d_in[12];
  float* out = (float*)d_out;

  const int N = in_sizes[0] / NFEAT;
  const int E = in_sizes[1];
  const int C2 = in_sizes[7] / NFEAT;  // 64

  // ---- carve workspace ----
  char* p = (char*)d_ws;
  auto carve = [&](size_t bytes) {
    char* q = p;
    p += align_up(bytes, 256);
    return q;
  };
  unsigned* slice_out = (unsigned*)carve((size_t)NXCD * N * 4);  // contiguous with slice_in
  unsigned* slice_in = (unsigned*)carve((size_t)NXCD * N * 4);
  int* cnt_in = (int*)carve((size_t)N * 4);
  int* row_ptr = (int*)carve((size_t)(N + 1) * 4);
  int* cursor = (int*)carve((size_t)N * 4);
  int* bsum = (int*)carve(512 * 4);
  int* bscan = (int*)carve(512 * 4);
  int* col = (int*)carve((size_t)E * 4);
  float* rsq_out = (float*)carve((size_t)N * 4);
  float* rsq_in = (float*)carve((size_t)N * 4);
  float* bn_sum0 = (float*)carve(128 * 4);
  float* bn_sumsq0 = (float*)carve(128 * 4);
  float* bn_sum1 = (float*)carve(128 * 4);
  float* bn_sumsq1 = (float*)carve(128 * 4);
  float* bn_scale0 = (float*)carve(128 * 4);
  float* bn_shift0 = (float*)carve(128 * 4);
  float* bn_scale1 = (float*)carve(128 * 4);
  float* bn_shift1 = (float*)carve(128 * 4);
  float* bufA = (float*)carve((size_t)N * NFEAT * 4);
  float* bufB = (float*)carve((size_t)N * NFEAT * 4);

  // ---- zero-init (ws is poisoned 0xAA every launch) ----
  hipMemsetAsync(slice_out, 0, (size_t)2 * NXCD * N * 4, stream);  // both slices contiguous
  hipMemsetAsync(bn_sum0, 0, 4 * 128 * 4, stream);                 // bn_sum0..bn_sumsq1 contiguous

  const int NB = (N + 255) / 256;

  // ---- degrees + CSR build ----
  k_hist8<<<2048, 256, 0, stream>>>(src, dst, slice_out, slice_in, E, N);
  k_rsq8<<<NB, 256, 0, stream>>>(slice_out, slice_in, rsq_out, rsq_in, cnt_in, N);
  k_scan1<<<NB, 256, 0, stream>>>(cnt_in, row_ptr, bsum, N);
  k_scan2<<<1, 512, 0, stream>>>(bsum, bscan, NB);
  k_scan3<<<NB, 256, 0, stream>>>(row_ptr, bscan, cursor, N, E);
  k_scatter<<<2048, 256, 0, stream>>>(src, dst, cursor, col, E);

  const int GR = (N + GB_ROWS - 1) / GB_ROWS;

  // ---- layer 0 ----
  k_gemm<<<dim3(GR, NFEAT / GB_COLS), 256, 0, stream>>>(in_feat, W0, bufA, rsq_out,
                                                        nullptr, nullptr, N, NFEAT, 0);
  k_spmm<NFEAT><<<(N + 7) / 8, 256, 0, stream>>>(row_ptr, col, bufA, bufB, rsq_in, b0, N);
  k_bn_stats<<<512, 256, 0, stream>>>(bufB, bn_sum0, bn_sumsq0, N);
  k_bn_final<<<1, 128, 0, stream>>>(bn_sum0, bn_sumsq0, gamma0, beta0, bn_scale0, bn_shift0, N);

  // ---- layer 1 ----
  k_gemm<<<dim3(GR, NFEAT / GB_COLS), 256, 0, stream>>>(bufB, W1, bufA, rsq_out,
                                                        bn_scale0, bn_shift0, N, NFEAT, 1);
  k_spmm<NFEAT><<<(N + 7) / 8, 256, 0, stream>>>(row_ptr, col, bufA, bufB, rsq_in, b1, N);
  k_bn_stats<<<512, 256, 0, stream>>>(bufB, bn_sum1, bn_sumsq1, N);
  k_bn_final<<<1, 128, 0, stream>>>(bn_sum1, bn_sumsq1, gamma1, beta1, bn_scale1, bn_shift1, N);

  // ---- layer 2 (output 64 classes) ----
  k_gemm<<<dim3(GR, 1), 256, 0, stream>>>(bufB, W2, bufA, rsq_out,
                                          bn_scale1, bn_shift1, N, C2, 1);
  k_spmm<64><<<(N + 15) / 16, 256, 0, stream>>>(row_ptr, col, bufA, out, rsq_in, b2, N);
}

// Round 4
// 694.691 us; speedup vs baseline: 1.2700x; 1.2700x over previous
//
#include <hip/hip_runtime.h>

#define NFEAT 128
#define BT 2048        // edges per bucketing block
#define BSH 9          // log2(nodes per bucket)
#define BSZ 512        // nodes per bucket

static inline size_t align_up(size_t x, size_t a) { return (x + a - 1) & ~(a - 1); }

// ---------------- K1: per-block bucket histograms (dst>>9 and src>>9), no global atomics ----
__global__ __launch_bounds__(256) void k_bcount(const int* __restrict__ src,
                                                const int* __restrict__ dst,
                                                int* __restrict__ cnt, int E, int nb, int NBK) {
  __shared__ int hD[256], hS[256];
  const int t = threadIdx.x, b = blockIdx.x;
  hD[t] = 0; hS[t] = 0;
  __syncthreads();
  const int e0 = b * BT, e1 = min(E, e0 + BT);
  for (int e = e0 + t; e < e1; e += 256) {
    atomicAdd(&hD[dst[e] >> BSH], 1);
    atomicAdd(&hS[src[e] >> BSH], 1);
  }
  __syncthreads();
  if (t < NBK) {
    cnt[t * nb + b] = hD[t];
    cnt[(NBK + t) * nb + b] = hS[t];
  }
}

// ---------------- exclusive scan over count matrix (3 phases) ----------------
__global__ __launch_bounds__(512) void k_scanA(const int* __restrict__ in,
                                               int* __restrict__ out,
                                               int* __restrict__ bsum, int n) {
  __shared__ int tmp[512];
  const int t = threadIdx.x;
  const int i = blockIdx.x * 512 + t;
  int v = (i < n) ? in[i] : 0;
  tmp[t] = v;
  __syncthreads();
  for (int off = 1; off < 512; off <<= 1) {
    int y = (t >= off) ? tmp[t - off] : 0;
    __syncthreads();
    tmp[t] += y;
    __syncthreads();
  }
  int incl = tmp[t];
  if (i < n) out[i] = incl - v;
  if (t == 511) bsum[blockIdx.x] = incl;
}

__global__ __launch_bounds__(1024) void k_scanB(const int* __restrict__ bsum,
                                                int* __restrict__ bscan, int nb1) {
  __shared__ int tmp[1024];
  const int t = threadIdx.x;
  int v = (t < nb1) ? bsum[t] : 0;
  tmp[t] = v;
  __syncthreads();
  for (int off = 1; off < 1024; off <<= 1) {
    int y = (t >= off) ? tmp[t - off] : 0;
    __syncthreads();
    tmp[t] += y;
    __syncthreads();
  }
  bscan[t] = tmp[t] - v;
}

__global__ __launch_bounds__(512) void k_scanC(int* __restrict__ out,
                                               const int* __restrict__ bscan, int n) {
  const int i = blockIdx.x * 512 + threadIdx.x;
  if (i < n) out[i] += bscan[blockIdx.x];
}

// ---------------- K2: place edges into bucketed arrays via LDS cursors ----------------
// buf[0,E): packed (dstLow<<17 | src), dst-bucket order.  buf[E,2E): src values, src-bucket order.
__global__ __launch_bounds__(256) void k_bplace(const int* __restrict__ src,
                                                const int* __restrict__ dst,
                                                const int* __restrict__ off,
                                                int* __restrict__ buf, int E, int nb, int NBK) {
  __shared__ int cD[256], cS[256];
  const int t = threadIdx.x, b = blockIdx.x;
  if (t < NBK) {
    cD[t] = off[t * nb + b];
    cS[t] = off[(NBK + t) * nb + b];
  }
  __syncthreads();
  const int e0 = b * BT, e1 = min(E, e0 + BT);
  for (int e = e0 + t; e < e1; e += 256) {
    int s = src[e];
    int d = dst[e];
    int pD = atomicAdd(&cD[d >> BSH], 1);          // LDS atomic
    buf[pD] = ((d & (BSZ - 1)) << 17) | s;
    int pS = atomicAdd(&cS[s >> BSH], 1);          // LDS atomic
    buf[pS] = s;
  }
}

// ---------------- K4: per-bucket CSR finish (row_ptr, rsq_in, col) ----------------
__global__ __launch_bounds__(256) void k_bcsr(const int* __restrict__ buf,
                                              const int* __restrict__ off,
                                              int* __restrict__ row_ptr,
                                              float* __restrict__ rsq_in,
                                              int* __restrict__ col,
                                              int E, int nb, int NBK, int N) {
  const int k = blockIdx.x, t = threadIdx.x;
  const int lo = off[k * nb];
  const int hi = (k + 1 < NBK) ? off[(k + 1) * nb] : E;
  __shared__ int cnt[BSZ];
  __shared__ int sc[BSZ];
  __shared__ int part[64];
  cnt[t] = 0; cnt[t + 256] = 0;
  __syncthreads();
  for (int e = lo + t; e < hi; e += 256) atomicAdd(&cnt[((unsigned)buf[e]) >> 17], 1);
  __syncthreads();
  if (t < 64) {
    int r = 0;
#pragma unroll
    for (int j = 0; j < 8; ++j) r += cnt[t * 8 + j];
    part[t] = r;
  }
  __syncthreads();
  if (t == 0) {
    int run = 0;
    for (int i = 0; i < 64; ++i) { int v = part[i]; part[i] = run; run += v; }
  }
  __syncthreads();
  if (t < 64) {
    int run = part[t];
#pragma unroll
    for (int j = 0; j < 8; ++j) { int v = cnt[t * 8 + j]; sc[t * 8 + j] = run; run += v; }
  }
  __syncthreads();
  for (int idx = t; idx < BSZ; idx += 256) {
    int n = (k << BSH) + idx;
    if (n < N) {
      row_ptr[n] = lo + sc[idx];
      int c = cnt[idx]; if (c < 1) c = 1;
      rsq_in[n] = 1.0f / sqrtf((float)c);
    }
    cnt[idx] = sc[idx];   // reset as cursor (each idx owned by one thread in both loops)
  }
  if (k == NBK - 1 && t == 0) row_ptr[N] = E;
  __syncthreads();
  for (int e = lo + t; e < hi; e += 256) {
    int w = buf[e];
    int p = atomicAdd(&cnt[((unsigned)w) >> 17], 1);  // LDS atomic
    col[lo + p] = w & 0x1FFFF;
  }
}

// ---------------- K5: per-bucket src-degree -> rsq_out ----------------
__global__ __launch_bounds__(256) void k_bdeg(const int* __restrict__ buf,
                                              const int* __restrict__ off,
                                              float* __restrict__ rsq_out,
                                              int E, int nb, int NBK, int N) {
  const int k = blockIdx.x, t = threadIdx.x;
  const int lo = off[(NBK + k) * nb];
  const int hi = (k + 1 < NBK) ? off[(NBK + k + 1) * nb] : 2 * E;
  __shared__ int cnt[BSZ];
  cnt[t] = 0; cnt[t + 256] = 0;
  __syncthreads();
  for (int e = lo + t; e < hi; e += 256) atomicAdd(&cnt[buf[e] & (BSZ - 1)], 1);
  __syncthreads();
  for (int idx = t; idx < BSZ; idx += 256) {
    int n = (k << BSH) + idx;
    if (n < N) {
      int c = cnt[idx]; if (c < 1) c = 1;
      rsq_out[n] = 1.0f / sqrtf((float)c);
    }
  }
}

// ---------------- fused pre-transform + SGEMM (unchanged) ----------------
#define GB_ROWS 64
#define GB_COLS 64
#define GK 16
#define XLD 68

__global__ __launch_bounds__(256) void k_gemm(
    const float* __restrict__ X, const float* __restrict__ W,
    float* __restrict__ Y, const float* __restrict__ rsq_out,
    const float* __restrict__ bnscale, const float* __restrict__ bnshift,
    int Nrows, int Ccols, int mode) {
  __shared__ __align__(16) float Xs[GK][XLD];
  __shared__ __align__(16) float Ws[GK][XLD];
  const int tid = threadIdx.x;
  const int tx = tid & 15;
  const int ty = tid >> 4;
  const int rowBase = blockIdx.x * GB_ROWS;
  const int colBase = blockIdx.y * GB_COLS;
  float acc[4][4] = {};

  for (int k0 = 0; k0 < NFEAT; k0 += GK) {
#pragma unroll
    for (int i = 0; i < 4; ++i) {
      int e = tid + i * 256;
      int r = e >> 4, k = e & 15;
      int gr = rowBase + r;
      float v = 0.0f;
      if (gr < Nrows) v = X[(size_t)gr * NFEAT + k0 + k];
      if (mode) {
        v = v * bnscale[k0 + k] + bnshift[k0 + k];
        v = v > 0.0f ? v : 0.0f;
      }
      Xs[k][r] = v;
    }
#pragma unroll
    for (int i = 0; i < 4; ++i) {
      int e = tid + i * 256;
      int k = e >> 6, c = e & 63;
      Ws[k][c] = W[(size_t)(k0 + k) * Ccols + colBase + c];
    }
    __syncthreads();
#pragma unroll
    for (int k = 0; k < GK; ++k) {
      const float4 xv = *(const float4*)&Xs[k][ty * 4];
      const float4 wv = *(const float4*)&Ws[k][tx * 4];
      acc[0][0] += xv.x * wv.x; acc[0][1] += xv.x * wv.y; acc[0][2] += xv.x * wv.z; acc[0][3] += xv.x * wv.w;
      acc[1][0] += xv.y * wv.x; acc[1][1] += xv.y * wv.y; acc[1][2] += xv.y * wv.z; acc[1][3] += xv.y * wv.w;
      acc[2][0] += xv.z * wv.x; acc[2][1] += xv.z * wv.y; acc[2][2] += xv.z * wv.z; acc[2][3] += xv.z * wv.w;
      acc[3][0] += xv.w * wv.x; acc[3][1] += xv.w * wv.y; acc[3][2] += xv.w * wv.z; acc[3][3] += xv.w * wv.w;
    }
    __syncthreads();
  }
#pragma unroll
  for (int i = 0; i < 4; ++i) {
    int gr = rowBase + ty * 4 + i;
    if (gr < Nrows) {
      float s = rsq_out[gr];
      float4 o = make_float4(acc[i][0] * s, acc[i][1] * s, acc[i][2] * s, acc[i][3] * s);
      *(float4*)&Y[(size_t)gr * Ccols + colBase + tx * 4] = o;
    }
  }
}

// ---------------- CSR SpMM (unchanged) ----------------
template <int F>
__global__ __launch_bounds__(256) void k_spmm(const int* __restrict__ row_ptr,
                                              const int* __restrict__ colidx,
                                              const float* __restrict__ xW,
                                              float* __restrict__ out,
                                              const float* __restrict__ rsq_in,
                                              const float* __restrict__ bias, int Nrows) {
  constexpr int L = F / 4;
  const int node = blockIdx.x * (256 / L) + threadIdx.x / L;
  const int lane = threadIdx.x % L;
  if (node >= Nrows) return;
  const int e0 = row_ptr[node];
  const int e1 = row_ptr[node + 1];
  float4 acc = make_float4(0.f, 0.f, 0.f, 0.f);
  int e = e0;
  for (; e + 1 < e1; e += 2) {
    int s0 = colidx[e];
    int s1 = colidx[e + 1];
    float4 v0 = *(const float4*)&xW[(size_t)s0 * F + lane * 4];
    float4 v1 = *(const float4*)&xW[(size_t)s1 * F + lane * 4];
    acc.x += v0.x; acc.y += v0.y; acc.z += v0.z; acc.w += v0.w;
    acc.x += v1.x; acc.y += v1.y; acc.z += v1.z; acc.w += v1.w;
  }
  if (e < e1) {
    int s0 = colidx[e];
    float4 v0 = *(const float4*)&xW[(size_t)s0 * F + lane * 4];
    acc.x += v0.x; acc.y += v0.y; acc.z += v0.z; acc.w += v0.w;
  }
  const float sc = rsq_in[node];
  const float4 b = *(const float4*)&bias[lane * 4];
  float4 o = make_float4(acc.x * sc + b.x, acc.y * sc + b.y, acc.z * sc + b.z, acc.w * sc + b.w);
  *(float4*)&out[(size_t)node * F + lane * 4] = o;
}

// ---------------- BatchNorm stats + finalize (unchanged) ----------------
__global__ __launch_bounds__(256) void k_bn_stats(const float* __restrict__ h,
                                                  float* __restrict__ sum,
                                                  float* __restrict__ sumsq, int Nrows) {
  const int f = threadIdx.x & 127;
  const int half = threadIdx.x >> 7;
  float s = 0.f, ss = 0.f;
  for (int r = blockIdx.x * 2 + half; r < Nrows; r += gridDim.x * 2) {
    float v = h[(size_t)r * NFEAT + f];
    s += v;
    ss += v * v;
  }
  __shared__ float ls[256], lss[256];
  ls[threadIdx.x] = s;
  lss[threadIdx.x] = ss;
  __syncthreads();
  if (half == 0) {
    atomicAdd(&sum[f], ls[f] + ls[f + 128]);
    atomicAdd(&sumsq[f], lss[f] + lss[f + 128]);
  }
}

__global__ __launch_bounds__(128) void k_bn_final(const float* __restrict__ sum,
                                                  const float* __restrict__ sumsq,
                                                  const float* __restrict__ gamma,
                                                  const float* __restrict__ beta,
                                                  float* __restrict__ scale,
                                                  float* __restrict__ shift, int Nrows) {
  int f = threadIdx.x;
  float inv_n = 1.0f / (float)Nrows;
  float mean = sum[f] * inv_n;
  float var = sumsq[f] * inv_n - mean * mean;
  if (var < 0.f) var = 0.f;
  float sc = gamma[f] * (1.0f / sqrtf(var + 1e-5f));
  scale[f] = sc;
  shift[f] = beta[f] - mean * sc;
}

extern "C" void kernel_launch(void* const* d_in, const int* in_sizes, int n_in,
                              void* d_out, int out_size, void* d_ws, size_t ws_size,
                              hipStream_t stream) {
  const float* in_feat = (const float*)d_in[0];
  const int* src = (const int*)d_in[1];
  const int* dst = (const int*)d_in[2];
  const float* W0 = (const float*)d_in[3];
  const float* b0 = (const float*)d_in[4];
  const float* W1 = (const float*)d_in[5];
  const float* b1 = (const float*)d_in[6];
  const float* W2 = (const float*)d_in[7];
  const float* b2 = (const float*)d_in[8];
  const float* gamma0 = (const float*)d_in[9];
  const float* beta0 = (const float*)d_in[10];
  const float* gamma1 = (const float*)d_in[11];
  const float* beta1 = (const float*)d_in[12];
  float* out = (float*)d_out;

  const int N = in_sizes[0] / NFEAT;
  const int E = in_sizes[1];
  const int C2 = in_sizes[7] / NFEAT;  // 64

  const int nb = (E + BT - 1) / BT;          // bucketing blocks
  const int NBK = (N + BSZ - 1) / BSZ;       // buckets (<=256)
  const int L = 2 * NBK * nb;                // count-matrix length
  const int nb1 = (L + 511) / 512;           // scan blocks (<=1024)

  // ---- carve workspace ----
  char* p = (char*)d_ws;
  auto carve = [&](size_t bytes) {
    char* q = p;
    p += align_up(bytes, 256);
    return q;
  };
  int* cnt = (int*)carve((size_t)L * 4);
  int* off = (int*)carve((size_t)L * 4);
  int* bsum = (int*)carve(1024 * 4);
  int* bscan = (int*)carve(1024 * 4);
  int* row_ptr = (int*)carve((size_t)(N + 1) * 4);
  int* col = (int*)carve((size_t)E * 4);
  float* rsq_out = (float*)carve((size_t)N * 4);
  float* rsq_in = (float*)carve((size_t)N * 4);
  float* bn_sum0 = (float*)carve(128 * 4);
  float* bn_sumsq0 = (float*)carve(128 * 4);
  float* bn_sum1 = (float*)carve(128 * 4);
  float* bn_sumsq1 = (float*)carve(128 * 4);
  float* bn_scale0 = (float*)carve(128 * 4);
  float* bn_shift0 = (float*)carve(128 * 4);
  float* bn_scale1 = (float*)carve(128 * 4);
  float* bn_shift1 = (float*)carve(128 * 4);
  float* bufA = (float*)carve((size_t)N * NFEAT * 4);
  float* bufB = (float*)carve((size_t)N * NFEAT * 4);
  int* buf = (int*)bufA;  // alias: bucketed edge arrays (2E ints) dead before GEMM writes bufA

  // ---- zero-init (ws poisoned 0xAA every launch) ----
  hipMemsetAsync(bn_sum0, 0, 4 * 128 * 4, stream);  // bn_sum0..bn_sumsq1 contiguous

  // ---- atomic-free CSR + degree pipeline ----
  k_bcount<<<nb, 256, 0, stream>>>(src, dst, cnt, E, nb, NBK);
  k_scanA<<<nb1, 512, 0, stream>>>(cnt, off, bsum, L);
  k_scanB<<<1, 1024, 0, stream>>>(bsum, bscan, nb1);
  k_scanC<<<nb1, 512, 0, stream>>>(off, bscan, L);
  k_bplace<<<nb, 256, 0, stream>>>(src, dst, off, buf, E, nb, NBK);
  k_bcsr<<<NBK, 256, 0, stream>>>(buf, off, row_ptr, rsq_in, col, E, nb, NBK, N);
  k_bdeg<<<NBK, 256, 0, stream>>>(buf, off, rsq_out, E, nb, NBK, N);

  const int GR = (N + GB_ROWS - 1) / GB_ROWS;

  // ---- layer 0 ----
  k_gemm<<<dim3(GR, NFEAT / GB_COLS), 256, 0, stream>>>(in_feat, W0, bufA, rsq_out,
                                                        nullptr, nullptr, N, NFEAT, 0);
  k_spmm<NFEAT><<<(N + 7) / 8, 256, 0, stream>>>(row_ptr, col, bufA, bufB, rsq_in, b0, N);
  k_bn_stats<<<512, 256, 0, stream>>>(bufB, bn_sum0, bn_sumsq0, N);
  k_bn_final<<<1, 128, 0, stream>>>(bn_sum0, bn_sumsq0, gamma0, beta0, bn_scale0, bn_shift0, N);

  // ---- layer 1 ----
  k_gemm<<<dim3(GR, NFEAT / GB_COLS), 256, 0, stream>>>(bufB, W1, bufA, rsq_out,
                                                        bn_scale0, bn_shift0, N, NFEAT, 1);
  k_spmm<NFEAT><<<(N + 7) / 8, 256, 0, stream>>>(row_ptr, col, bufA, bufB, rsq_in, b1, N);
  k_bn_stats<<<512, 256, 0, stream>>>(bufB, bn_sum1, bn_sumsq1, N);
  k_bn_final<<<1, 128, 0, stream>>>(bn_sum1, bn_sumsq1, gamma1, beta1, bn_scale1, bn_shift1, N);

  // ---- layer 2 (output 64 classes) ----
  k_gemm<<<dim3(GR, 1), 256, 0, stream>>>(bufB, W2, bufA, rsq_out,
                                          bn_scale1, bn_shift1, N, C2, 1);
  k_spmm<64><<<(N + 15) / 16, 256, 0, stream>>>(row_ptr, col, bufA, out, rsq_in, b2, N);
}

// Round 6
// 571.939 us; speedup vs baseline: 1.5426x; 1.2146x over previous
//
#include <hip/hip_runtime.h>

#define NFEAT 128
#define BT 2048        // edges per bucketing block
#define BSH 9          // log2(nodes per bucket)
#define BSZ 512        // nodes per bucket

static inline size_t align_up(size_t x, size_t a) { return (x + a - 1) & ~(a - 1); }

__device__ inline unsigned short f2bf(float f) {  // RNE float->bf16
  unsigned u = __float_as_uint(f);
  u += 0x7FFF + ((u >> 16) & 1);
  return (unsigned short)(u >> 16);
}

// ---------------- K1: per-block bucket histograms (dst>>9 and src>>9), no global atomics ----
__global__ __launch_bounds__(256) void k_bcount(const int* __restrict__ src,
                                                const int* __restrict__ dst,
                                                int* __restrict__ cnt, int E, int nb, int NBK) {
  __shared__ int hD[256], hS[256];
  const int t = threadIdx.x, b = blockIdx.x;
  hD[t] = 0; hS[t] = 0;
  __syncthreads();
  const int e0 = b * BT, e1 = min(E, e0 + BT);
  for (int e = e0 + t; e < e1; e += 256) {
    atomicAdd(&hD[dst[e] >> BSH], 1);
    atomicAdd(&hS[src[e] >> BSH], 1);
  }
  __syncthreads();
  if (t < NBK) {
    cnt[t * nb + b] = hD[t];
    cnt[(NBK + t) * nb + b] = hS[t];
  }
}

// ---------------- exclusive scan over count matrix (3 phases) ----------------
__global__ __launch_bounds__(512) void k_scanA(const int* __restrict__ in,
                                               int* __restrict__ out,
                                               int* __restrict__ bsum, int n) {
  __shared__ int tmp[512];
  const int t = threadIdx.x;
  const int i = blockIdx.x * 512 + t;
  int v = (i < n) ? in[i] : 0;
  tmp[t] = v;
  __syncthreads();
  for (int off = 1; off < 512; off <<= 1) {
    int y = (t >= off) ? tmp[t - off] : 0;
    __syncthreads();
    tmp[t] += y;
    __syncthreads();
  }
  int incl = tmp[t];
  if (i < n) out[i] = incl - v;
  if (t == 511) bsum[blockIdx.x] = incl;
}

__global__ __launch_bounds__(1024) void k_scanB(const int* __restrict__ bsum,
                                                int* __restrict__ bscan, int nb1) {
  __shared__ int tmp[1024];
  const int t = threadIdx.x;
  int v = (t < nb1) ? bsum[t] : 0;
  tmp[t] = v;
  __syncthreads();
  for (int off = 1; off < 1024; off <<= 1) {
    int y = (t >= off) ? tmp[t - off] : 0;
    __syncthreads();
    tmp[t] += y;
    __syncthreads();
  }
  bscan[t] = tmp[t] - v;
}

__global__ __launch_bounds__(512) void k_scanC(int* __restrict__ out,
                                               const int* __restrict__ bscan, int n) {
  const int i = blockIdx.x * 512 + threadIdx.x;
  if (i < n) out[i] += bscan[blockIdx.x];
}

// ---------------- K2: place edges into bucketed arrays via LDS cursors ----------------
// buf[0,E): packed (dstLow<<17 | src), dst-bucket order.  buf[E,2E): src values, src-bucket order.
__global__ __launch_bounds__(256) void k_bplace(const int* __restrict__ src,
                                                const int* __restrict__ dst,
                                                const int* __restrict__ off,
                                                int* __restrict__ buf, int E, int nb, int NBK) {
  __shared__ int cD[256], cS[256];
  const int t = threadIdx.x, b = blockIdx.x;
  if (t < NBK) {
    cD[t] = off[t * nb + b];
    cS[t] = off[(NBK + t) * nb + b];
  }
  __syncthreads();
  const int e0 = b * BT, e1 = min(E, e0 + BT);
  for (int e = e0 + t; e < e1; e += 256) {
    int s = src[e];
    int d = dst[e];
    int pD = atomicAdd(&cD[d >> BSH], 1);          // LDS atomic
    buf[pD] = ((d & (BSZ - 1)) << 17) | s;
    int pS = atomicAdd(&cS[s >> BSH], 1);          // LDS atomic
    buf[pS] = s;
  }
}

// ---------------- K4: per-bucket CSR finish (row_ptr, rsq_in, col) ----------------
__global__ __launch_bounds__(256) void k_bcsr(const int* __restrict__ buf,
                                              const int* __restrict__ off,
                                              int* __restrict__ row_ptr,
                                              float* __restrict__ rsq_in,
                                              int* __restrict__ col,
                                              int E, int nb, int NBK, int N) {
  const int k = blockIdx.x, t = threadIdx.x;
  const int lo = off[k * nb];
  const int hi = (k + 1 < NBK) ? off[(k + 1) * nb] : E;
  __shared__ int cnt[BSZ];
  __shared__ int sc[BSZ];
  __shared__ int part[64];
  cnt[t] = 0; cnt[t + 256] = 0;
  __syncthreads();
  for (int e = lo + t; e < hi; e += 256) atomicAdd(&cnt[((unsigned)buf[e]) >> 17], 1);
  __syncthreads();
  if (t < 64) {
    int r = 0;
#pragma unroll
    for (int j = 0; j < 8; ++j) r += cnt[t * 8 + j];
    part[t] = r;
  }
  __syncthreads();
  if (t == 0) {
    int run = 0;
    for (int i = 0; i < 64; ++i) { int v = part[i]; part[i] = run; run += v; }
  }
  __syncthreads();
  if (t < 64) {
    int run = part[t];
#pragma unroll
    for (int j = 0; j < 8; ++j) { int v = cnt[t * 8 + j]; sc[t * 8 + j] = run; run += v; }
  }
  __syncthreads();
  for (int idx = t; idx < BSZ; idx += 256) {
    int n = (k << BSH) + idx;
    if (n < N) {
      row_ptr[n] = lo + sc[idx];
      int c = cnt[idx]; if (c < 1) c = 1;
      rsq_in[n] = 1.0f / sqrtf((float)c);
    }
    cnt[idx] = sc[idx];   // reset as cursor (each idx owned by one thread in both loops)
  }
  if (k == NBK - 1 && t == 0) row_ptr[N] = E;
  __syncthreads();
  for (int e = lo + t; e < hi; e += 256) {
    int w = buf[e];
    int p = atomicAdd(&cnt[((unsigned)w) >> 17], 1);  // LDS atomic
    col[lo + p] = w & 0x1FFFF;
  }
}

// ---------------- K5: per-bucket src-degree -> rsq_out ----------------
__global__ __launch_bounds__(256) void k_bdeg(const int* __restrict__ buf,
                                              const int* __restrict__ off,
                                              float* __restrict__ rsq_out,
                                              int E, int nb, int NBK, int N) {
  const int k = blockIdx.x, t = threadIdx.x;
  const int lo = off[(NBK + k) * nb];
  const int hi = (k + 1 < NBK) ? off[(NBK + k + 1) * nb] : 2 * E;
  __shared__ int cnt[BSZ];
  cnt[t] = 0; cnt[t + 256] = 0;
  __syncthreads();
  for (int e = lo + t; e < hi; e += 256) atomicAdd(&cnt[buf[e] & (BSZ - 1)], 1);
  __syncthreads();
  for (int idx = t; idx < BSZ; idx += 256) {
    int n = (k << BSH) + idx;
    if (n < N) {
      int c = cnt[idx]; if (c < 1) c = 1;
      rsq_out[n] = 1.0f / sqrtf((float)c);
    }
  }
}

// ---------------- fused pre-transform + SGEMM, bf16 output ----------------
// Ybf[r][c] = bf16( rsq_out[r] * sum_k f(X[r][k]) * W[k][c] )
#define GB_ROWS 64
#define GB_COLS 64
#define GK 16
#define XLD 68

__global__ __launch_bounds__(256) void k_gemm(
    const float* __restrict__ X, const float* __restrict__ W,
    unsigned short* __restrict__ Ybf, const float* __restrict__ rsq_out,
    const float* __restrict__ bnscale, const float* __restrict__ bnshift,
    int Nrows, int Ccols, int mode) {
  __shared__ __align__(16) float Xs[GK][XLD];
  __shared__ __align__(16) float Ws[GK][XLD];
  const int tid = threadIdx.x;
  const int tx = tid & 15;
  const int ty = tid >> 4;
  const int rowBase = blockIdx.x * GB_ROWS;
  const int colBase = blockIdx.y * GB_COLS;
  float acc[4][4] = {};

  for (int k0 = 0; k0 < NFEAT; k0 += GK) {
#pragma unroll
    for (int i = 0; i < 4; ++i) {
      int e = tid + i * 256;
      int r = e >> 4, k = e & 15;
      int gr = rowBase + r;
      float v = 0.0f;
      if (gr < Nrows) v = X[(size_t)gr * NFEAT + k0 + k];
      if (mode) {
        v = v * bnscale[k0 + k] + bnshift[k0 + k];
        v = v > 0.0f ? v : 0.0f;
      }
      Xs[k][r] = v;
    }
#pragma unroll
    for (int i = 0; i < 4; ++i) {
      int e = tid + i * 256;
      int k = e >> 6, c = e & 63;
      Ws[k][c] = W[(size_t)(k0 + k) * Ccols + colBase + c];
    }
    __syncthreads();
#pragma unroll
    for (int k = 0; k < GK; ++k) {
      const float4 xv = *(const float4*)&Xs[k][ty * 4];
      const float4 wv = *(const float4*)&Ws[k][tx * 4];
      acc[0][0] += xv.x * wv.x; acc[0][1] += xv.x * wv.y; acc[0][2] += xv.x * wv.z; acc[0][3] += xv.x * wv.w;
      acc[1][0] += xv.y * wv.x; acc[1][1] += xv.y * wv.y; acc[1][2] += xv.y * wv.z; acc[1][3] += xv.y * wv.w;
      acc[2][0] += xv.z * wv.x; acc[2][1] += xv.z * wv.y; acc[2][2] += xv.z * wv.z; acc[2][3] += xv.z * wv.w;
      acc[3][0] += xv.w * wv.x; acc[3][1] += xv.w * wv.y; acc[3][2] += xv.w * wv.z; acc[3][3] += xv.w * wv.w;
    }
    __syncthreads();
  }
#pragma unroll
  for (int i = 0; i < 4; ++i) {
    int gr = rowBase + ty * 4 + i;
    if (gr < Nrows) {
      float s = rsq_out[gr];
      ushort4 o;
      o.x = f2bf(acc[i][0] * s);
      o.y = f2bf(acc[i][1] * s);
      o.z = f2bf(acc[i][2] * s);
      o.w = f2bf(acc[i][3] * s);
      *(ushort4*)&Ybf[(size_t)gr * Ccols + colBase + tx * 4] = o;
    }
  }
}

// ---------------- CSR SpMM over bf16 rows, fp32 accumulate ----------------
// out[n] = rsq_in[n] * sum_{e in row n} xWbf[col[e]] + bias
template <int F>
__global__ __launch_bounds__(256) void k_spmm_bf(const int* __restrict__ row_ptr,
                                                 const int* __restrict__ colidx,
                                                 const unsigned short* __restrict__ xW,
                                                 float* __restrict__ out,
                                                 const float* __restrict__ rsq_in,
                                                 const float* __restrict__ bias, int Nrows) {
  constexpr int L = F / 8;  // lanes per node, 16 B (8 bf16) each
  const int node = blockIdx.x * (256 / L) + threadIdx.x / L;
  const int lane = threadIdx.x % L;
  if (node >= Nrows) return;
  const int e0 = row_ptr[node];
  const int e1 = row_ptr[node + 1];
  float acc[8] = {};
  int e = e0;
  for (; e + 1 < e1; e += 2) {
    int s0 = colidx[e];
    int s1 = colidx[e + 1];
    uint4 v0 = *(const uint4*)&xW[(size_t)s0 * F + lane * 8];
    uint4 v1 = *(const uint4*)&xW[(size_t)s1 * F + lane * 8];
    acc[0] += __uint_as_float(v0.x << 16); acc[1] += __uint_as_float(v0.x & 0xFFFF0000u);
    acc[2] += __uint_as_float(v0.y << 16); acc[3] += __uint_as_float(v0.y & 0xFFFF0000u);
    acc[4] += __uint_as_float(v0.z << 16); acc[5] += __uint_as_float(v0.z & 0xFFFF0000u);
    acc[6] += __uint_as_float(v0.w << 16); acc[7] += __uint_as_float(v0.w & 0xFFFF0000u);
    acc[0] += __uint_as_float(v1.x << 16); acc[1] += __uint_as_float(v1.x & 0xFFFF0000u);
    acc[2] += __uint_as_float(v1.y << 16); acc[3] += __uint_as_float(v1.y & 0xFFFF0000u);
    acc[4] += __uint_as_float(v1.z << 16); acc[5] += __uint_as_float(v1.z & 0xFFFF0000u);
    acc[6] += __uint_as_float(v1.w << 16); acc[7] += __uint_as_float(v1.w & 0xFFFF0000u);
  }
  if (e < e1) {
    int s0 = colidx[e];
    uint4 v0 = *(const uint4*)&xW[(size_t)s0 * F + lane * 8];
    acc[0] += __uint_as_float(v0.x << 16); acc[1] += __uint_as_float(v0.x & 0xFFFF0000u);
    acc[2] += __uint_as_float(v0.y << 16); acc[3] += __uint_as_float(v0.y & 0xFFFF0000u);
    acc[4] += __uint_as_float(v0.z << 16); acc[5] += __uint_as_float(v0.z & 0xFFFF0000u);
    acc[6] += __uint_as_float(v0.w << 16); acc[7] += __uint_as_float(v0.w & 0xFFFF0000u);
  }
  const float sc = rsq_in[node];
  float4 oA, oB;
  const float4 bA = *(const float4*)&bias[lane * 8];
  const float4 bB = *(const float4*)&bias[lane * 8 + 4];
  oA.x = acc[0] * sc + bA.x; oA.y = acc[1] * sc + bA.y;
  oA.z = acc[2] * sc + bA.z; oA.w = acc[3] * sc + bA.w;
  oB.x = acc[4] * sc + bB.x; oB.y = acc[5] * sc + bB.y;
  oB.z = acc[6] * sc + bB.z; oB.w = acc[7] * sc + bB.w;
  *(float4*)&out[(size_t)node * F + lane * 8] = oA;
  *(float4*)&out[(size_t)node * F + lane * 8 + 4] = oB;
}

// ---------------- BatchNorm stats + finalize (unchanged) ----------------
__global__ __launch_bounds__(256) void k_bn_stats(const float* __restrict__ h,
                                                  float* __restrict__ sum,
                                                  float* __restrict__ sumsq, int Nrows) {
  const int f = threadIdx.x & 127;
  const int half = threadIdx.x >> 7;
  float s = 0.f, ss = 0.f;
  for (int r = blockIdx.x * 2 + half; r < Nrows; r += gridDim.x * 2) {
    float v = h[(size_t)r * NFEAT + f];
    s += v;
    ss += v * v;
  }
  __shared__ float ls[256], lss[256];
  ls[threadIdx.x] = s;
  lss[threadIdx.x] = ss;
  __syncthreads();
  if (half == 0) {
    atomicAdd(&sum[f], ls[f] + ls[f + 128]);
    atomicAdd(&sumsq[f], lss[f] + lss[f + 128]);
  }
}

__global__ __launch_bounds__(128) void k_bn_final(const float* __restrict__ sum,
                                                  const float* __restrict__ sumsq,
                                                  const float* __restrict__ gamma,
                                                  const float* __restrict__ beta,
                                                  float* __restrict__ scale,
                                                  float* __restrict__ shift, int Nrows) {
  int f = threadIdx.x;
  float inv_n = 1.0f / (float)Nrows;
  float mean = sum[f] * inv_n;
  float var = sumsq[f] * inv_n - mean * mean;
  if (var < 0.f) var = 0.f;
  float sc = gamma[f] * (1.0f / sqrtf(var + 1e-5f));
  scale[f] = sc;
  shift[f] = beta[f] - mean * sc;
}

extern "C" void kernel_launch(void* const* d_in, const int* in_sizes, int n_in,
                              void* d_out, int out_size, void* d_ws, size_t ws_size,
                              hipStream_t stream) {
  const float* in_feat = (const float*)d_in[0];
  const int* src = (const int*)d_in[1];
  const int* dst = (const int*)d_in[2];
  const float* W0 = (const float*)d_in[3];
  const float* b0 = (const float*)d_in[4];
  const float* W1 = (const float*)d_in[5];
  const float* b1 = (const float*)d_in[6];
  const float* W2 = (const float*)d_in[7];
  const float* b2 = (const float*)d_in[8];
  const float* gamma0 = (const float*)d_in[9];
  const float* beta0 = (const float*)d_in[10];
  const float* gamma1 = (const float*)d_in[11];
  const float* beta1 = (const float*)d_in[12];
  float* out = (float*)d_out;

  const int N = in_sizes[0] / NFEAT;
  const int E = in_sizes[1];
  const int C2 = in_sizes[7] / NFEAT;  // 64

  const int nb = (E + BT - 1) / BT;          // bucketing blocks
  const int NBK = (N + BSZ - 1) / BSZ;       // buckets (<=256)
  const int L = 2 * NBK * nb;                // count-matrix length
  const int nb1 = (L + 511) / 512;           // scan blocks (<=1024)

  // ---- carve workspace ----
  char* p = (char*)d_ws;
  auto carve = [&](size_t bytes) {
    char* q = p;
    p += align_up(bytes, 256);
    return q;
  };
  int* cnt = (int*)carve((size_t)L * 4);
  int* off = (int*)carve((size_t)L * 4);
  int* bsum = (int*)carve(1024 * 4);
  int* bscan = (int*)carve(1024 * 4);
  int* row_ptr = (int*)carve((size_t)(N + 1) * 4);
  int* col = (int*)carve((size_t)E * 4);
  float* rsq_out = (float*)carve((size_t)N * 4);
  float* rsq_in = (float*)carve((size_t)N * 4);
  float* bn_sum0 = (float*)carve(128 * 4);
  float* bn_sumsq0 = (float*)carve(128 * 4);
  float* bn_sum1 = (float*)carve(128 * 4);
  float* bn_sumsq1 = (float*)carve(128 * 4);
  float* bn_scale0 = (float*)carve(128 * 4);
  float* bn_shift0 = (float*)carve(128 * 4);
  float* bn_scale1 = (float*)carve(128 * 4);
  float* bn_shift1 = (float*)carve(128 * 4);
  unsigned short* xWbf = (unsigned short*)carve((size_t)N * NFEAT * 2);  // bf16 GEMM out
  float* bufB = (float*)carve((size_t)N * NFEAT * 4);                    // fp32 h
  int* buf = (int*)carve((size_t)2 * E * 4);                             // bucketed edges

  // ---- zero-init (ws poisoned 0xAA every launch) ----
  hipMemsetAsync(bn_sum0, 0, 4 * 128 * 4, stream);  // bn_sum0..bn_sumsq1 contiguous

  // ---- atomic-free CSR + degree pipeline ----
  k_bcount<<<nb, 256, 0, stream>>>(src, dst, cnt, E, nb, NBK);
  k_scanA<<<nb1, 512, 0, stream>>>(cnt, off, bsum, L);
  k_scanB<<<1, 1024, 0, stream>>>(bsum, bscan, nb1);
  k_scanC<<<nb1, 512, 0, stream>>>(off, bscan, L);
  k_bplace<<<nb, 256, 0, stream>>>(src, dst, off, buf, E, nb, NBK);
  k_bcsr<<<NBK, 256, 0, stream>>>(buf, off, row_ptr, rsq_in, col, E, nb, NBK, N);
  k_bdeg<<<NBK, 256, 0, stream>>>(buf, off, rsq_out, E, nb, NBK, N);

  const int GR = (N + GB_ROWS - 1) / GB_ROWS;

  // ---- layer 0 ----
  k_gemm<<<dim3(GR, NFEAT / GB_COLS), 256, 0, stream>>>(in_feat, W0, xWbf, rsq_out,
                                                        nullptr, nullptr, N, NFEAT, 0);
  k_spmm_bf<NFEAT><<<(N + 15) / 16, 256, 0, stream>>>(row_ptr, col, xWbf, bufB, rsq_in, b0, N);
  k_bn_stats<<<512, 256, 0, stream>>>(bufB, bn_sum0, bn_sumsq0, N);
  k_bn_final<<<1, 128, 0, stream>>>(bn_sum0, bn_sumsq0, gamma0, beta0, bn_scale0, bn_shift0, N);

  // ---- layer 1 ----
  k_gemm<<<dim3(GR, NFEAT / GB_COLS), 256, 0, stream>>>(bufB, W1, xWbf, rsq_out,
                                                        bn_scale0, bn_shift0, N, NFEAT, 1);
  k_spmm_bf<NFEAT><<<(N + 15) / 16, 256, 0, stream>>>(row_ptr, col, xWbf, bufB, rsq_in, b1, N);
  k_bn_stats<<<512, 256, 0, stream>>>(bufB, bn_sum1, bn_sumsq1, N);
  k_bn_final<<<1, 128, 0, stream>>>(bn_sum1, bn_sumsq1, gamma1, beta1, bn_scale1, bn_shift1, N);

  // ---- layer 2 (output 64 classes) ----
  k_gemm<<<dim3(GR, 1), 256, 0, stream>>>(bufB, W2, xWbf, rsq_out,
                                          bn_scale1, bn_shift1, N, C2, 1);
  k_spmm_bf<64><<<(N + 31) / 32, 256, 0, stream>>>(row_ptr, col, xWbf, out, rsq_in, b2, N);
}

// Round 8
// 516.503 us; speedup vs baseline: 1.7081x; 1.1073x over previous
//
#include <hip/hip_runtime.h>

#define NFEAT 128
#define BT 2048        // edges per bucketing block
#define BSH 9          // log2(nodes per bucket)
#define BSZ 512        // nodes per bucket

typedef __attribute__((ext_vector_type(8))) short short8v;
typedef __attribute__((ext_vector_type(4))) float float4v;

static inline size_t align_up(size_t x, size_t a) { return (x + a - 1) & ~(a - 1); }

__device__ inline unsigned short f2bf(float f) {  // RNE float->bf16
  unsigned u = __float_as_uint(f);
  u += 0x7FFF + ((u >> 16) & 1);
  return (unsigned short)(u >> 16);
}

// ---------------- K1: per-block bucket histograms (dst>>9 and src>>9), no global atomics ----
__global__ __launch_bounds__(256) void k_bcount(const int* __restrict__ src,
                                                const int* __restrict__ dst,
                                                int* __restrict__ cnt, int E, int nb, int NBK) {
  __shared__ int hD[256], hS[256];
  const int t = threadIdx.x, b = blockIdx.x;
  hD[t] = 0; hS[t] = 0;
  __syncthreads();
  const int e0 = b * BT, e1 = min(E, e0 + BT);
  for (int e = e0 + t; e < e1; e += 256) {
    atomicAdd(&hD[dst[e] >> BSH], 1);
    atomicAdd(&hS[src[e] >> BSH], 1);
  }
  __syncthreads();
  if (t < NBK) {
    cnt[t * nb + b] = hD[t];
    cnt[(NBK + t) * nb + b] = hS[t];
  }
}

// ---------------- exclusive scan over count matrix (3 phases) ----------------
__global__ __launch_bounds__(512) void k_scanA(const int* __restrict__ in,
                                               int* __restrict__ out,
                                               int* __restrict__ bsum, int n) {
  __shared__ int tmp[512];
  const int t = threadIdx.x;
  const int i = blockIdx.x * 512 + t;
  int v = (i < n) ? in[i] : 0;
  tmp[t] = v;
  __syncthreads();
  for (int off = 1; off < 512; off <<= 1) {
    int y = (t >= off) ? tmp[t - off] : 0;
    __syncthreads();
    tmp[t] += y;
    __syncthreads();
  }
  int incl = tmp[t];
  if (i < n) out[i] = incl - v;
  if (t == 511) bsum[blockIdx.x] = incl;
}

__global__ __launch_bounds__(1024) void k_scanB(const int* __restrict__ bsum,
                                                int* __restrict__ bscan, int nb1) {
  __shared__ int tmp[1024];
  const int t = threadIdx.x;
  int v = (t < nb1) ? bsum[t] : 0;
  tmp[t] = v;
  __syncthreads();
  for (int off = 1; off < 1024; off <<= 1) {
    int y = (t >= off) ? tmp[t - off] : 0;
    __syncthreads();
    tmp[t] += y;
    __syncthreads();
  }
  bscan[t] = tmp[t] - v;
}

__global__ __launch_bounds__(512) void k_scanC(int* __restrict__ out,
                                               const int* __restrict__ bscan, int n) {
  const int i = blockIdx.x * 512 + threadIdx.x;
  if (i < n) out[i] += bscan[blockIdx.x];
}

// ---------------- K2: place edges into bucketed arrays via LDS cursors ----------------
__global__ __launch_bounds__(256) void k_bplace(const int* __restrict__ src,
                                                const int* __restrict__ dst,
                                                const int* __restrict__ off,
                                                int* __restrict__ buf, int E, int nb, int NBK) {
  __shared__ int cD[256], cS[256];
  const int t = threadIdx.x, b = blockIdx.x;
  if (t < NBK) {
    cD[t] = off[t * nb + b];
    cS[t] = off[(NBK + t) * nb + b];
  }
  __syncthreads();
  const int e0 = b * BT, e1 = min(E, e0 + BT);
  for (int e = e0 + t; e < e1; e += 256) {
    int s = src[e];
    int d = dst[e];
    int pD = atomicAdd(&cD[d >> BSH], 1);          // LDS atomic
    buf[pD] = ((d & (BSZ - 1)) << 17) | s;
    int pS = atomicAdd(&cS[s >> BSH], 1);          // LDS atomic
    buf[pS] = s;
  }
}

// ---------------- K4: per-bucket CSR finish (row_ptr, rsq_in, col) ----------------
__global__ __launch_bounds__(256) void k_bcsr(const int* __restrict__ buf,
                                              const int* __restrict__ off,
                                              int* __restrict__ row_ptr,
                                              float* __restrict__ rsq_in,
                                              int* __restrict__ col,
                                              int E, int nb, int NBK, int N) {
  const int k = blockIdx.x, t = threadIdx.x;
  const int lo = off[k * nb];
  const int hi = (k + 1 < NBK) ? off[(k + 1) * nb] : E;
  __shared__ int cnt[BSZ];
  __shared__ int sc[BSZ];
  __shared__ int part[64];
  cnt[t] = 0; cnt[t + 256] = 0;
  __syncthreads();
  for (int e = lo + t; e < hi; e += 256) atomicAdd(&cnt[((unsigned)buf[e]) >> 17], 1);
  __syncthreads();
  if (t < 64) {
    int r = 0;
#pragma unroll
    for (int j = 0; j < 8; ++j) r += cnt[t * 8 + j];
    part[t] = r;
  }
  __syncthreads();
  if (t == 0) {
    int run = 0;
    for (int i = 0; i < 64; ++i) { int v = part[i]; part[i] = run; run += v; }
  }
  __syncthreads();
  if (t < 64) {
    int run = part[t];
#pragma unroll
    for (int j = 0; j < 8; ++j) { int v = cnt[t * 8 + j]; sc[t * 8 + j] = run; run += v; }
  }
  __syncthreads();
  for (int idx = t; idx < BSZ; idx += 256) {
    int n = (k << BSH) + idx;
    if (n < N) {
      row_ptr[n] = lo + sc[idx];
      int c = cnt[idx]; if (c < 1) c = 1;
      rsq_in[n] = 1.0f / sqrtf((float)c);
    }
    cnt[idx] = sc[idx];   // reset as cursor (each idx owned by one thread in both loops)
  }
  if (k == NBK - 1 && t == 0) row_ptr[N] = E;
  __syncthreads();
  for (int e = lo + t; e < hi; e += 256) {
    int w = buf[e];
    int p = atomicAdd(&cnt[((unsigned)w) >> 17], 1);  // LDS atomic
    col[lo + p] = w & 0x1FFFF;
  }
}

// ---------------- K5: per-bucket src-degree -> rsq_out ----------------
__global__ __launch_bounds__(256) void k_bdeg(const int* __restrict__ buf,
                                              const int* __restrict__ off,
                                              float* __restrict__ rsq_out,
                                              int E, int nb, int NBK, int N) {
  const int k = blockIdx.x, t = threadIdx.x;
  const int lo = off[(NBK + k) * nb];
  const int hi = (k + 1 < NBK) ? off[(NBK + k + 1) * nb] : 2 * E;
  __shared__ int cnt[BSZ];
  cnt[t] = 0; cnt[t + 256] = 0;
  __syncthreads();
  for (int e = lo + t; e < hi; e += 256) atomicAdd(&cnt[buf[e] & (BSZ - 1)], 1);
  __syncthreads();
  for (int idx = t; idx < BSZ; idx += 256) {
    int n = (k << BSH) + idx;
    if (n < N) {
      int c = cnt[idx]; if (c < 1) c = 1;
      rsq_out[n] = 1.0f / sqrtf((float)c);
    }
  }
}

// ---------------- W prep: transpose + bf16 convert (runs once per launch, trivial) -------
__global__ __launch_bounds__(256) void k_wprep(const float* __restrict__ W0,
                                               const float* __restrict__ W1,
                                               const float* __restrict__ W2,
                                               unsigned short* __restrict__ Wt0,
                                               unsigned short* __restrict__ Wt1,
                                               unsigned short* __restrict__ Wt2) {
  int t = blockIdx.x * 256 + threadIdx.x;
  if (t < 16384) {                      // W0: [128][128] -> Wt0[c][k]
    int c = t >> 7, k = t & 127;
    Wt0[c * 128 + k] = f2bf(W0[k * 128 + c]);
  } else if (t < 32768) {               // W1
    int u = t - 16384;
    int c = u >> 7, k = u & 127;
    Wt1[c * 128 + k] = f2bf(W1[k * 128 + c]);
  } else if (t < 40960) {               // W2: [128][64] -> Wt2[c][k], c<64
    int u = t - 32768;
    int c = u >> 7, k = u & 127;
    Wt2[c * 128 + k] = f2bf(W2[k * 64 + c]);
  }
}

// ---------------- MFMA GEMM: Ybf[r][c] = bf16( rsq_out[r] * sum_k f(X[r][k]) * W[k][c] ) --
// 64 rows/block, CC cols (full width), K=128. 4 waves, each wave 16 rows x CC cols.
// LDS: Xbf[64][128] + Wt[CC][128], both row-major-K with XOR swizzle byte^=((row&7)<<4).
template <int CC>
__global__ __launch_bounds__(256) void k_gemm_mfma(
    const float* __restrict__ X, const unsigned short* __restrict__ Wt,
    unsigned short* __restrict__ Ybf, const float* __restrict__ rsq_out,
    const float* __restrict__ bnscale, const float* __restrict__ bnshift,
    int Nrows, int mode) {
  constexpr int XBYTES = 64 * 256;          // 16 KB
  constexpr int WBYTES = CC * 256;          // 32 or 16 KB
  __shared__ __align__(16) char lds[XBYTES + WBYTES];
  const int tid = threadIdx.x;
  const int rowBase = blockIdx.x * 64;

  // ---- stage W tile (bf16, pre-transposed [c][k]), b128 copies, swizzled dest ----
  for (int u = tid; u < CC * 16; u += 256) {
    int c = u >> 4, kq = u & 15;
    uint4 v = *(const uint4*)(Wt + c * 128 + kq * 8);
    int byte = (c * 256 + kq * 16) ^ ((c & 7) << 4);
    *(uint4*)(&lds[XBYTES + byte]) = v;
  }
  // ---- stage X tile: 64 rows x 128 k, transform + cvt, ushort4 writes, swizzled ----
#pragma unroll
  for (int i = 0; i < 8; ++i) {
    int u = tid + i * 256;                  // 2048 float4-units
    int r = u >> 5, kq = u & 31;
    int gr = rowBase + r;
    float4 v = make_float4(0.f, 0.f, 0.f, 0.f);
    if (gr < Nrows) v = *(const float4*)(X + (size_t)gr * 128 + kq * 4);
    if (mode) {
      const float4 s = *(const float4*)(bnscale + kq * 4);
      const float4 h = *(const float4*)(bnshift + kq * 4);
      v.x = fmaxf(v.x * s.x + h.x, 0.f);
      v.y = fmaxf(v.y * s.y + h.y, 0.f);
      v.z = fmaxf(v.z * s.z + h.z, 0.f);
      v.w = fmaxf(v.w * s.w + h.w, 0.f);
    }
    ushort4 o;
    o.x = f2bf(v.x); o.y = f2bf(v.y); o.z = f2bf(v.z); o.w = f2bf(v.w);
    int byte = (r * 256 + kq * 8) ^ ((r & 7) << 4);
    *(ushort4*)(&lds[byte]) = o;
  }
  __syncthreads();

  const int wv = tid >> 6;                  // wave 0..3
  const int l = tid & 63;
  const int l16 = l & 15, lk = l >> 4;

  // ---- A fragments: row = wv*16 + l16, k = kk*32 + lk*8 .. +8 ----
  short8v a[4];
  const int arow = wv * 16 + l16;
#pragma unroll
  for (int kk = 0; kk < 4; ++kk) {
    int byte = (arow * 256 + kk * 64 + lk * 16) ^ ((arow & 7) << 4);
    a[kk] = *(const short8v*)(&lds[byte]);
  }

  float4v acc[CC / 16];
#pragma unroll
  for (int ct = 0; ct < CC / 16; ++ct) acc[ct] = (float4v){0.f, 0.f, 0.f, 0.f};

#pragma unroll
  for (int ct = 0; ct < CC / 16; ++ct) {
    const int col = ct * 16 + l16;
#pragma unroll
    for (int kk = 0; kk < 4; ++kk) {
      int byte = XBYTES + ((col * 256 + kk * 64 + lk * 16) ^ ((col & 7) << 4));
      short8v b = *(const short8v*)(&lds[byte]);
      acc[ct] = __builtin_amdgcn_mfma_f32_16x16x32_bf16(a[kk], b, acc[ct], 0, 0, 0);
    }
  }

  // ---- epilogue: D row = wv*16 + lk*4 + r, col = ct*16 + l16 ----
  const int row0 = rowBase + wv * 16 + lk * 4;
  float scr[4];
#pragma unroll
  for (int r = 0; r < 4; ++r) scr[r] = (row0 + r < Nrows) ? rsq_out[row0 + r] : 0.f;
#pragma unroll
  for (int ct = 0; ct < CC / 16; ++ct) {
#pragma unroll
    for (int r = 0; r < 4; ++r) {
      int row = row0 + r;
      if (row < Nrows)
        Ybf[(size_t)row * CC + ct * 16 + l16] = f2bf(acc[ct][r] * scr[r]);
    }
  }
}

// ---------------- CSR SpMM over bf16 rows, fp32 accumulate (unchanged) ----------------
template <int F>
__global__ __launch_bounds__(256) void k_spmm_bf(const int* __restrict__ row_ptr,
                                                 const int* __restrict__ colidx,
                                                 const unsigned short* __restrict__ xW,
                                                 float* __restrict__ out,
                                                 const float* __restrict__ rsq_in,
                                                 const float* __restrict__ bias, int Nrows) {
  constexpr int L = F / 8;  // lanes per node, 16 B (8 bf16) each
  const int node = blockIdx.x * (256 / L) + threadIdx.x / L;
  const int lane = threadIdx.x % L;
  if (node >= Nrows) return;
  const int e0 = row_ptr[node];
  const int e1 = row_ptr[node + 1];
  float acc[8] = {};
  int e = e0;
  for (; e + 1 < e1; e += 2) {
    int s0 = colidx[e];
    int s1 = colidx[e + 1];
    uint4 v0 = *(const uint4*)&xW[(size_t)s0 * F + lane * 8];
    uint4 v1 = *(const uint4*)&xW[(size_t)s1 * F + lane * 8];
    acc[0] += __uint_as_float(v0.x << 16); acc[1] += __uint_as_float(v0.x & 0xFFFF0000u);
    acc[2] += __uint_as_float(v0.y << 16); acc[3] += __uint_as_float(v0.y & 0xFFFF0000u);
    acc[4] += __uint_as_float(v0.z << 16); acc[5] += __uint_as_float(v0.z & 0xFFFF0000u);
    acc[6] += __uint_as_float(v0.w << 16); acc[7] += __uint_as_float(v0.w & 0xFFFF0000u);
    acc[0] += __uint_as_float(v1.x << 16); acc[1] += __uint_as_float(v1.x & 0xFFFF0000u);
    acc[2] += __uint_as_float(v1.y << 16); acc[3] += __uint_as_float(v1.y & 0xFFFF0000u);
    acc[4] += __uint_as_float(v1.z << 16); acc[5] += __uint_as_float(v1.z & 0xFFFF0000u);
    acc[6] += __uint_as_float(v1.w << 16); acc[7] += __uint_as_float(v1.w & 0xFFFF0000u);
  }
  if (e < e1) {
    int s0 = colidx[e];
    uint4 v0 = *(const uint4*)&xW[(size_t)s0 * F + lane * 8];
    acc[0] += __uint_as_float(v0.x << 16); acc[1] += __uint_as_float(v0.x & 0xFFFF0000u);
    acc[2] += __uint_as_float(v0.y << 16); acc[3] += __uint_as_float(v0.y & 0xFFFF0000u);
    acc[4] += __uint_as_float(v0.z << 16); acc[5] += __uint_as_float(v0.z & 0xFFFF0000u);
    acc[6] += __uint_as_float(v0.w << 16); acc[7] += __uint_as_float(v0.w & 0xFFFF0000u);
  }
  const float sc = rsq_in[node];
  float4 oA, oB;
  const float4 bA = *(const float4*)&bias[lane * 8];
  const float4 bB = *(const float4*)&bias[lane * 8 + 4];
  oA.x = acc[0] * sc + bA.x; oA.y = acc[1] * sc + bA.y;
  oA.z = acc[2] * sc + bA.z; oA.w = acc[3] * sc + bA.w;
  oB.x = acc[4] * sc + bB.x; oB.y = acc[5] * sc + bB.y;
  oB.z = acc[6] * sc + bB.z; oB.w = acc[7] * sc + bB.w;
  *(float4*)&out[(size_t)node * F + lane * 8] = oA;
  *(float4*)&out[(size_t)node * F + lane * 8 + 4] = oB;
}

// ---------------- BatchNorm stats + finalize (unchanged) ----------------
__global__ __launch_bounds__(256) void k_bn_stats(const float* __restrict__ h,
                                                  float* __restrict__ sum,
                                                  float* __restrict__ sumsq, int Nrows) {
  const int f = threadIdx.x & 127;
  const int half = threadIdx.x >> 7;
  float s = 0.f, ss = 0.f;
  for (int r = blockIdx.x * 2 + half; r < Nrows; r += gridDim.x * 2) {
    float v = h[(size_t)r * NFEAT + f];
    s += v;
    ss += v * v;
  }
  __shared__ float ls[256], lss[256];
  ls[threadIdx.x] = s;
  lss[threadIdx.x] = ss;
  __syncthreads();
  if (half == 0) {
    atomicAdd(&sum[f], ls[f] + ls[f + 128]);
    atomicAdd(&sumsq[f], lss[f] + lss[f + 128]);
  }
}

__global__ __launch_bounds__(128) void k_bn_final(const float* __restrict__ sum,
                                                  const float* __restrict__ sumsq,
                                                  const float* __restrict__ gamma,
                                                  const float* __restrict__ beta,
                                                  float* __restrict__ scale,
                                                  float* __restrict__ shift, int Nrows) {
  int f = threadIdx.x;
  float inv_n = 1.0f / (float)Nrows;
  float mean = sum[f] * inv_n;
  float var = sumsq[f] * inv_n - mean * mean;
  if (var < 0.f) var = 0.f;
  float sc = gamma[f] * (1.0f / sqrtf(var + 1e-5f));
  scale[f] = sc;
  shift[f] = beta[f] - mean * sc;
}

extern "C" void kernel_launch(void* const* d_in, const int* in_sizes, int n_in,
                              void* d_out, int out_size, void* d_ws, size_t ws_size,
                              hipStream_t stream) {
  const float* in_feat = (const float*)d_in[0];
  const int* src = (const int*)d_in[1];
  const int* dst = (const int*)d_in[2];
  const float* W0 = (const float*)d_in[3];
  const float* b0 = (const float*)d_in[4];
  const float* W1 = (const float*)d_in[5];
  const float* b1 = (const float*)d_in[6];
  const float* W2 = (const float*)d_in[7];
  const float* b2 = (const float*)d_in[8];
  const float* gamma0 = (const float*)d_in[9];
  const float* beta0 = (const float*)d_in[10];
  const float* gamma1 = (const float*)d_in[11];
  const float* beta1 = (const float*)d_in[12];
  float* out = (float*)d_out;

  const int N = in_sizes[0] / NFEAT;
  const int E = in_sizes[1];

  const int nb = (E + BT - 1) / BT;          // bucketing blocks
  const int NBK = (N + BSZ - 1) / BSZ;       // buckets (<=256)
  const int L = 2 * NBK * nb;                // count-matrix length
  const int nb1 = (L + 511) / 512;           // scan blocks (<=1024)

  // ---- carve workspace ----
  char* p = (char*)d_ws;
  auto carve = [&](size_t bytes) {
    char* q = p;
    p += align_up(bytes, 256);
    return q;
  };
  int* cnt = (int*)carve((size_t)L * 4);
  int* off = (int*)carve((size_t)L * 4);
  int* bsum = (int*)carve(1024 * 4);
  int* bscan = (int*)carve(1024 * 4);
  int* row_ptr = (int*)carve((size_t)(N + 1) * 4);
  int* col = (int*)carve((size_t)E * 4);
  float* rsq_out = (float*)carve((size_t)N * 4);
  float* rsq_in = (float*)carve((size_t)N * 4);
  float* bn_sum0 = (float*)carve(128 * 4);
  float* bn_sumsq0 = (float*)carve(128 * 4);
  float* bn_sum1 = (float*)carve(128 * 4);
  float* bn_sumsq1 = (float*)carve(128 * 4);
  float* bn_scale0 = (float*)carve(128 * 4);
  float* bn_shift0 = (float*)carve(128 * 4);
  float* bn_scale1 = (float*)carve(128 * 4);
  float* bn_shift1 = (float*)carve(128 * 4);
  unsigned short* Wt0 = (unsigned short*)carve(16384 * 2);
  unsigned short* Wt1 = (unsigned short*)carve(16384 * 2);
  unsigned short* Wt2 = (unsigned short*)carve(8192 * 2);
  unsigned short* xWbf = (unsigned short*)carve((size_t)N * NFEAT * 2);  // bf16 GEMM out
  float* bufB = (float*)carve((size_t)N * NFEAT * 4);                    // fp32 h
  int* buf = (int*)carve((size_t)2 * E * 4);                             // bucketed edges

  // ---- zero-init (ws poisoned 0xAA every launch) ----
  hipMemsetAsync(bn_sum0, 0, 4 * 128 * 4, stream);  // bn_sum0..bn_sumsq1 contiguous

  // ---- W prep + atomic-free CSR + degree pipeline ----
  k_wprep<<<160, 256, 0, stream>>>(W0, W1, W2, Wt0, Wt1, Wt2);
  k_bcount<<<nb, 256, 0, stream>>>(src, dst, cnt, E, nb, NBK);
  k_scanA<<<nb1, 512, 0, stream>>>(cnt, off, bsum, L);
  k_scanB<<<1, 1024, 0, stream>>>(bsum, bscan, nb1);
  k_scanC<<<nb1, 512, 0, stream>>>(off, bscan, L);
  k_bplace<<<nb, 256, 0, stream>>>(src, dst, off, buf, E, nb, NBK);
  k_bcsr<<<NBK, 256, 0, stream>>>(buf, off, row_ptr, rsq_in, col, E, nb, NBK, N);
  k_bdeg<<<NBK, 256, 0, stream>>>(buf, off, rsq_out, E, nb, NBK, N);

  const int GR = (N + 63) / 64;

  // ---- layer 0 ----
  k_gemm_mfma<128><<<GR, 256, 0, stream>>>(in_feat, Wt0, xWbf, rsq_out,
                                           nullptr, nullptr, N, 0);
  k_spmm_bf<NFEAT><<<(N + 15) / 16, 256, 0, stream>>>(row_ptr, col, xWbf, bufB, rsq_in, b0, N);
  k_bn_stats<<<512, 256, 0, stream>>>(bufB, bn_sum0, bn_sumsq0, N);
  k_bn_final<<<1, 128, 0, stream>>>(bn_sum0, bn_sumsq0, gamma0, beta0, bn_scale0, bn_shift0, N);

  // ---- layer 1 ----
  k_gemm_mfma<128><<<GR, 256, 0, stream>>>(bufB, Wt1, xWbf, rsq_out,
                                           bn_scale0, bn_shift0, N, 1);
  k_spmm_bf<NFEAT><<<(N + 15) / 16, 256, 0, stream>>>(row_ptr, col, xWbf, bufB, rsq_in, b1, N);
  k_bn_stats<<<512, 256, 0, stream>>>(bufB, bn_sum1, bn_sumsq1, N);
  k_bn_final<<<1, 128, 0, stream>>>(bn_sum1, bn_sumsq1, gamma1, beta1, bn_scale1, bn_shift1, N);

  // ---- layer 2 (output 64 classes) ----
  k_gemm_mfma<64><<<GR, 256, 0, stream>>>(bufB, Wt2, xWbf, rsq_out,
                                          bn_scale1, bn_shift1, N, 1);
  k_spmm_bf<64><<<(N + 31) / 32, 256, 0, stream>>>(row_ptr, col, xWbf, out, rsq_in, b2, N);
}